// Round 2
// 2018.143 us; speedup vs baseline: 1.0325x; 1.0325x over previous
//
#include <hip/hip_runtime.h>
#include <math.h>

#define BB 64
#define TT 2048
#define II 256
#define HH 256
#define OO 128

// ---------------------------------------------------------------------------
// GEMM with bias: C[m,n] = sum_k A[m,k] * W[n,k] + b1[n] + b2[n]
// (unchanged; only used for xp1)
// ---------------------------------------------------------------------------
template<int N>
__global__ __launch_bounds__(256)
void gemm_bias(const float* __restrict__ A, const float* __restrict__ W,
               const float* __restrict__ b1, const float* __restrict__ b2,
               float* __restrict__ C)
{
    constexpr int K = 256;
    __shared__ float sA[16][132];
    __shared__ float sB[16][132];
    const int tid  = threadIdx.x;
    const long row0 = (long)blockIdx.x * 128;
    const int  col0 = blockIdx.y * 128;

    const int tm = tid & 15;
    const int tn = tid >> 4;

    float acc[8][8];
#pragma unroll
    for (int i = 0; i < 8; ++i)
#pragma unroll
        for (int j = 0; j < 8; ++j) acc[i][j] = 0.f;

    const int f0  = tid;
    const int f1  = tid + 256;
    const int am0 = f0 >> 2, ak0 = (f0 & 3) * 4;
    const int am1 = f1 >> 2, ak1 = (f1 & 3) * 4;

    for (int kt = 0; kt < K; kt += 16) {
        float4 a0 = *(const float4*)&A[(row0 + am0) * K + kt + ak0];
        float4 a1 = *(const float4*)&A[(row0 + am1) * K + kt + ak1];
        float4 w0 = *(const float4*)&W[(long)(col0 + am0) * K + kt + ak0];
        float4 w1 = *(const float4*)&W[(long)(col0 + am1) * K + kt + ak1];
        __syncthreads();
        sA[ak0+0][am0] = a0.x; sA[ak0+1][am0] = a0.y; sA[ak0+2][am0] = a0.z; sA[ak0+3][am0] = a0.w;
        sA[ak1+0][am1] = a1.x; sA[ak1+1][am1] = a1.y; sA[ak1+2][am1] = a1.z; sA[ak1+3][am1] = a1.w;
        sB[ak0+0][am0] = w0.x; sB[ak0+1][am0] = w0.y; sB[ak0+2][am0] = w0.z; sB[ak0+3][am0] = w0.w;
        sB[ak1+0][am1] = w1.x; sB[ak1+1][am1] = w1.y; sB[ak1+2][am1] = w1.z; sB[ak1+3][am1] = w1.w;
        __syncthreads();
#pragma unroll
        for (int k = 0; k < 16; ++k) {
            float4 av0 = *(const float4*)&sA[k][tm * 8];
            float4 av1 = *(const float4*)&sA[k][tm * 8 + 4];
            float4 bv0 = *(const float4*)&sB[k][tn * 8];
            float4 bv1 = *(const float4*)&sB[k][tn * 8 + 4];
            float am[8] = {av0.x, av0.y, av0.z, av0.w, av1.x, av1.y, av1.z, av1.w};
            float bn[8] = {bv0.x, bv0.y, bv0.z, bv0.w, bv1.x, bv1.y, bv1.z, bv1.w};
#pragma unroll
            for (int i = 0; i < 8; ++i)
#pragma unroll
                for (int j = 0; j < 8; ++j)
                    acc[i][j] += am[i] * bn[j];
        }
    }

    float bias[8];
#pragma unroll
    for (int j = 0; j < 8; ++j) {
        int col = col0 + tn * 8 + j;
        bias[j] = b1[col] + b2[col];
    }
#pragma unroll
    for (int i = 0; i < 8; ++i) {
        long row = row0 + tm * 8 + i;
        float4 v0, v1;
        v0.x = acc[i][0] + bias[0]; v0.y = acc[i][1] + bias[1];
        v0.z = acc[i][2] + bias[2]; v0.w = acc[i][3] + bias[3];
        v1.x = acc[i][4] + bias[4]; v1.y = acc[i][5] + bias[5];
        v1.z = acc[i][6] + bias[6]; v1.w = acc[i][7] + bias[7];
        *(float4*)&C[row * N + col0 + tn * 8]     = v0;
        *(float4*)&C[row * N + col0 + tn * 8 + 4] = v1;
    }
}

__device__ __forceinline__ float fast_tanh(float x) {
    float e = __expf(2.f * x);
    return 1.f - 2.f / (e + 1.f);
}

// ---------------------------------------------------------------------------
// Pipelined RNN: 128 WGs x 512 threads.
//   WG b in [0,64):    producer — layer-1 recurrence for batch b.
//   WG b+64:           consumer — layer-2 projection+recurrence for batch b,
//                      trailing the producer via flags[b].
// Round-1 changes:
//   * __launch_bounds__(512) (no min-waves arg): full 256-VGPR budget so the
//     128-float W_hh1 slice (and consumer's 96-float slices) stays resident.
//   * Consumer spin: tid==0 RELAXED poll; on success ONE acquire load
//     (establishes ordering with the producer's release store), broadcast
//     via LDS. The old all-thread ACQUIRE poll emitted a cache invalidate
//     per iteration per wave — an L2-inv storm thrashing producers' L2.
//   * Producer partial layout: two consecutive-float4 half-stripes
//     (ks*256+g*4 and ks*256+128+g*4) — conflict-free writes; gather offset
//     'ro' keeps the reduce at 2 lanes/bank (free).
// ---------------------------------------------------------------------------
__global__ __launch_bounds__(512)
void rnn_pipe(const float* __restrict__ W_hh1,
              const float* __restrict__ W_ih2,
              const float* __restrict__ W_hh2,
              const float* __restrict__ b_ih2,
              const float* __restrict__ b_hh2,
              float* __restrict__ XH,          // xp1 in / h1 out (in place)
              float* __restrict__ out,         // [B*T, OO]
              int* __restrict__ flags)         // [BB], pre-zeroed
{
    const int tid = threadIdx.x;
    const int g   = tid & 31;
    const int ks  = tid >> 5;

    if (blockIdx.x < BB) {
        // ------------------------- producer -------------------------------
        __shared__ float h_lds[256];
        __shared__ float part[16 * 256];
        const int b = blockIdx.x;

        float4 w[8][4];
#pragma unroll
        for (int r = 0; r < 8; ++r)
#pragma unroll
            for (int c = 0; c < 4; ++c)
                w[r][c] = *(const float4*)&W_hh1[(g * 8 + r) * 256 + ks * 16 + c * 4];

        float* rowp = XH + (long)b * TT * HH;
        float xp = 0.f;
        if (tid < 256) {
            h_lds[tid] = 0.f;
            xp = rowp[tid];
        }
        // gather offset for the half-stripe partial layout:
        // row n = g*8+r lives at (r>=4)*128 + g*4 + (r&3)
        const int ro = ((tid & 7) >> 2) * 128 + ((tid >> 3) << 2) + (tid & 3);
        __syncthreads();

        for (int t = 0; t < TT; ++t) {
            float4 h4[4];
#pragma unroll
            for (int c = 0; c < 4; ++c)
                h4[c] = *(const float4*)&h_lds[ks * 16 + c * 4];

            float acc[8];
#pragma unroll
            for (int r = 0; r < 8; ++r) acc[r] = 0.f;
#pragma unroll
            for (int c = 0; c < 4; ++c)
#pragma unroll
                for (int r = 0; r < 8; ++r)
                    acc[r] += w[r][c].x * h4[c].x + w[r][c].y * h4[c].y
                            + w[r][c].z * h4[c].z + w[r][c].w * h4[c].w;

            // conflict-free partial writes: consecutive float4 per ks-group
            *(float4*)&part[ks * 256 + g * 4]       = make_float4(acc[0], acc[1], acc[2], acc[3]);
            *(float4*)&part[ks * 256 + 128 + g * 4] = make_float4(acc[4], acc[5], acc[6], acc[7]);
            __syncthreads();

            if (tid < 256) {
                float s0 = part[0 * 256 + ro] + part[1 * 256 + ro]
                         + part[2 * 256 + ro] + part[3 * 256 + ro];
                float s1 = part[4 * 256 + ro] + part[5 * 256 + ro]
                         + part[6 * 256 + ro] + part[7 * 256 + ro];
                float s2 = part[8 * 256 + ro] + part[9 * 256 + ro]
                         + part[10 * 256 + ro] + part[11 * 256 + ro];
                float s3 = part[12 * 256 + ro] + part[13 * 256 + ro]
                         + part[14 * 256 + ro] + part[15 * 256 + ro];
                float v = fast_tanh(((s0 + s1) + (s2 + s3)) + xp);
                h_lds[tid] = v;
                rowp[(long)t * HH + tid] = v;
                if (t + 1 < TT) xp = rowp[(long)(t + 1) * HH + tid];
            }
            __syncthreads();

            // publish progress every 4 steps (release@agent pushes h1 rows
            // to the L3 coherence point)
            if ((t & 3) == 3 && tid == 0)
                __hip_atomic_store(&flags[b], t + 1, __ATOMIC_RELEASE,
                                   __HIP_MEMORY_SCOPE_AGENT);
        }
    } else {
        // ------------------------- consumer -------------------------------
        __shared__ float h1_lds[256];
        __shared__ float o_lds[128];
        __shared__ float part2[16 * 132];
        __shared__ int   seen_sh;
        const int b = blockIdx.x - BB;

        float4 wi[4][4];
        float4 wh[4][2];
#pragma unroll
        for (int r = 0; r < 4; ++r) {
#pragma unroll
            for (int c = 0; c < 4; ++c)
                wi[r][c] = *(const float4*)&W_ih2[(g * 4 + r) * 256 + ks * 16 + c * 4];
#pragma unroll
            for (int c = 0; c < 2; ++c)
                wh[r][c] = *(const float4*)&W_hh2[(g * 4 + r) * 128 + ks * 8 + c * 4];
        }

        float bias = 0.f;
        if (tid < 128) {
            bias = b_ih2[tid] + b_hh2[tid];
            o_lds[tid] = 0.f;
        }
        const float* h1p = XH + (long)b * TT * HH;
        float* outp      = out + (long)b * TT * OO;
        __syncthreads();

        int seen = 0;
        for (int t = 0; t < TT; ++t) {
            if (seen <= t) {
                // single-lane relaxed spin; ONE acquire load on success
                if (tid == 0) {
                    int s;
                    do {
                        s = __hip_atomic_load(&flags[b], __ATOMIC_RELAXED,
                                              __HIP_MEMORY_SCOPE_AGENT);
                    } while (s <= t);
                    s = __hip_atomic_load(&flags[b], __ATOMIC_ACQUIRE,
                                          __HIP_MEMORY_SCOPE_AGENT);
                    seen_sh = s;
                }
                __syncthreads();
                seen = seen_sh;
            }
            // stage h1_t into LDS (1 KB, 64 lanes x float4)
            if (tid < 64)
                *(float4*)&h1_lds[tid * 4] = *(const float4*)&h1p[(long)t * HH + tid * 4];
            __syncthreads();

            float4 h4[4];
#pragma unroll
            for (int c = 0; c < 4; ++c)
                h4[c] = *(const float4*)&h1_lds[ks * 16 + c * 4];
            float4 o4[2];
#pragma unroll
            for (int c = 0; c < 2; ++c)
                o4[c] = *(const float4*)&o_lds[ks * 8 + c * 4];

            float acc[4];
#pragma unroll
            for (int r = 0; r < 4; ++r) acc[r] = 0.f;
#pragma unroll
            for (int c = 0; c < 4; ++c)
#pragma unroll
                for (int r = 0; r < 4; ++r)
                    acc[r] += wi[r][c].x * h4[c].x + wi[r][c].y * h4[c].y
                            + wi[r][c].z * h4[c].z + wi[r][c].w * h4[c].w;
#pragma unroll
            for (int c = 0; c < 2; ++c)
#pragma unroll
                for (int r = 0; r < 4; ++r)
                    acc[r] += wh[r][c].x * o4[c].x + wh[r][c].y * o4[c].y
                            + wh[r][c].z * o4[c].z + wh[r][c].w * o4[c].w;

            *(float4*)&part2[ks * 132 + g * 4] = make_float4(acc[0], acc[1], acc[2], acc[3]);
            __syncthreads();

            if (tid < 128) {
                float s = bias;
#pragma unroll
                for (int s16 = 0; s16 < 16; ++s16)
                    s += part2[s16 * 132 + tid];
                float v = fast_tanh(s);
                o_lds[tid] = v;
                outp[(long)t * OO + tid] = v;
            }
            // o_lds / part2 reuse is fenced by the stage barrier at loop top
        }
    }
}

// ---------------------------------------------------------------------------
extern "C" void kernel_launch(void* const* d_in, const int* in_sizes, int n_in,
                              void* d_out, int out_size, void* d_ws, size_t ws_size,
                              hipStream_t stream)
{
    const float* x     = (const float*)d_in[0];
    const float* W_ih1 = (const float*)d_in[1];
    const float* W_hh1 = (const float*)d_in[2];
    const float* b_ih1 = (const float*)d_in[3];
    const float* b_hh1 = (const float*)d_in[4];
    const float* W_ih2 = (const float*)d_in[5];
    const float* W_hh2 = (const float*)d_in[6];
    const float* b_ih2 = (const float*)d_in[7];
    const float* b_hh2 = (const float*)d_in[8];
    float* out = (float*)d_out;

    float* xp1 = (float*)d_ws;                         // [B*T, 256] = 128 MiB
    const size_t FLAG_OFF = (size_t)BB * TT * HH * sizeof(float);
    int* flags = (int*)((char*)d_ws + FLAG_OFF);       // [64] ints

    const int M = BB * TT;                             // 131072

    (void)hipMemsetAsync(flags, 0, BB * sizeof(int), stream);

    // Phase A: xp1 = x @ W_ih1^T + b_ih1 + b_hh1   -> ws
    dim3 gA(M / 128, HH / 128);
    gemm_bias<HH><<<gA, 256, 0, stream>>>(x, W_ih1, b_ih1, b_hh1, xp1);

    // Phase B: pipelined layer-1 recurrence (producers) + fused
    //          projection+layer-2 recurrence (consumers)
    rnn_pipe<<<2 * BB, 512, 0, stream>>>(W_hh1, W_ih2, W_hh2, b_ih2, b_hh2,
                                         xp1, out, flags);
}

// Round 3
// 1923.085 us; speedup vs baseline: 1.0835x; 1.0494x over previous
//
#include <hip/hip_runtime.h>
#include <math.h>

#define BB 64
#define TT 2048
#define II 256
#define HH 256
#define OO 128

// ---------------------------------------------------------------------------
// GEMM with bias: C[m,n] = sum_k A[m,k] * W[n,k] + b1[n] + b2[n]
// (unchanged; only used for xp1)
// ---------------------------------------------------------------------------
template<int N>
__global__ __launch_bounds__(256)
void gemm_bias(const float* __restrict__ A, const float* __restrict__ W,
               const float* __restrict__ b1, const float* __restrict__ b2,
               float* __restrict__ C)
{
    constexpr int K = 256;
    __shared__ float sA[16][132];
    __shared__ float sB[16][132];
    const int tid  = threadIdx.x;
    const long row0 = (long)blockIdx.x * 128;
    const int  col0 = blockIdx.y * 128;

    const int tm = tid & 15;
    const int tn = tid >> 4;

    float acc[8][8];
#pragma unroll
    for (int i = 0; i < 8; ++i)
#pragma unroll
        for (int j = 0; j < 8; ++j) acc[i][j] = 0.f;

    const int f0  = tid;
    const int f1  = tid + 256;
    const int am0 = f0 >> 2, ak0 = (f0 & 3) * 4;
    const int am1 = f1 >> 2, ak1 = (f1 & 3) * 4;

    for (int kt = 0; kt < K; kt += 16) {
        float4 a0 = *(const float4*)&A[(row0 + am0) * K + kt + ak0];
        float4 a1 = *(const float4*)&A[(row0 + am1) * K + kt + ak1];
        float4 w0 = *(const float4*)&W[(long)(col0 + am0) * K + kt + ak0];
        float4 w1 = *(const float4*)&W[(long)(col0 + am1) * K + kt + ak1];
        __syncthreads();
        sA[ak0+0][am0] = a0.x; sA[ak0+1][am0] = a0.y; sA[ak0+2][am0] = a0.z; sA[ak0+3][am0] = a0.w;
        sA[ak1+0][am1] = a1.x; sA[ak1+1][am1] = a1.y; sA[ak1+2][am1] = a1.z; sA[ak1+3][am1] = a1.w;
        sB[ak0+0][am0] = w0.x; sB[ak0+1][am0] = w0.y; sB[ak0+2][am0] = w0.z; sB[ak0+3][am0] = w0.w;
        sB[ak1+0][am1] = w1.x; sB[ak1+1][am1] = w1.y; sB[ak1+2][am1] = w1.z; sB[ak1+3][am1] = w1.w;
        __syncthreads();
#pragma unroll
        for (int k = 0; k < 16; ++k) {
            float4 av0 = *(const float4*)&sA[k][tm * 8];
            float4 av1 = *(const float4*)&sA[k][tm * 8 + 4];
            float4 bv0 = *(const float4*)&sB[k][tn * 8];
            float4 bv1 = *(const float4*)&sB[k][tn * 8 + 4];
            float am[8] = {av0.x, av0.y, av0.z, av0.w, av1.x, av1.y, av1.z, av1.w};
            float bn[8] = {bv0.x, bv0.y, bv0.z, bv0.w, bv1.x, bv1.y, bv1.z, bv1.w};
#pragma unroll
            for (int i = 0; i < 8; ++i)
#pragma unroll
                for (int j = 0; j < 8; ++j)
                    acc[i][j] += am[i] * bn[j];
        }
    }

    float bias[8];
#pragma unroll
    for (int j = 0; j < 8; ++j) {
        int col = col0 + tn * 8 + j;
        bias[j] = b1[col] + b2[col];
    }
#pragma unroll
    for (int i = 0; i < 8; ++i) {
        long row = row0 + tm * 8 + i;
        float4 v0, v1;
        v0.x = acc[i][0] + bias[0]; v0.y = acc[i][1] + bias[1];
        v0.z = acc[i][2] + bias[2]; v0.w = acc[i][3] + bias[3];
        v1.x = acc[i][4] + bias[4]; v1.y = acc[i][5] + bias[5];
        v1.z = acc[i][6] + bias[6]; v1.w = acc[i][7] + bias[7];
        *(float4*)&C[row * N + col0 + tn * 8]     = v0;
        *(float4*)&C[row * N + col0 + tn * 8 + 4] = v1;
    }
}

__device__ __forceinline__ float fast_tanh(float x) {
    float e = __expf(2.f * x);
    return 1.f - 2.f / (e + 1.f);
}

// Light barrier: LDS-ordering only. Unlike __syncthreads(), does NOT drain
// vmcnt — global loads/stores stay in flight across it (T4 applied to RNN).
#define LIGHT_BARRIER() do {                                       \
    asm volatile("s_waitcnt lgkmcnt(0)" ::: "memory");             \
    __builtin_amdgcn_s_barrier();                                  \
} while (0)

// ---------------------------------------------------------------------------
// Pipelined RNN: 128 WGs x 512 threads.
//   WG b in [0,64):    producer — layer-1 recurrence for batch b.
//   WG b+64:           consumer — layer-2 projection+recurrence for batch b.
// Round-2 changes:
//   * All per-step __syncthreads() -> light barriers. hipcc's __syncthreads
//     emits s_waitcnt vmcnt(0) before s_barrier, serializing the h1-row
//     store ack + the L2-cold xp prefetch (~400-900 cyc) into EVERY step.
//   * xp prefetch 4-deep in registers (static index via 4x unroll), refilled
//     once per group — latency covered by ~4 steps of compute.
//   * Full vmcnt(0) drain only every 8 steps, right before the flag publish
//     (the drain is required there: all waves' h1 stores must be in L2
//     before tid0's release-store wbl2 pushes them to L3).
// ---------------------------------------------------------------------------
__global__ __launch_bounds__(512)
void rnn_pipe(const float* __restrict__ W_hh1,
              const float* __restrict__ W_ih2,
              const float* __restrict__ W_hh2,
              const float* __restrict__ b_ih2,
              const float* __restrict__ b_hh2,
              float* __restrict__ XH,          // xp1 in / h1 out (in place)
              float* __restrict__ out,         // [B*T, OO]
              int* __restrict__ flags)         // [BB], pre-zeroed
{
    const int tid = threadIdx.x;
    const int g   = tid & 31;
    const int ks  = tid >> 5;

    if (blockIdx.x < BB) {
        // ------------------------- producer -------------------------------
        __shared__ float h_lds[256];
        __shared__ float part[16 * 256];
        const int b = blockIdx.x;

        float4 w[8][4];
#pragma unroll
        for (int r = 0; r < 8; ++r)
#pragma unroll
            for (int c = 0; c < 4; ++c)
                w[r][c] = *(const float4*)&W_hh1[(g * 8 + r) * 256 + ks * 16 + c * 4];

        float* rowp = XH + (long)b * TT * HH;
        float xpb[4] = {0.f, 0.f, 0.f, 0.f};
        if (tid < 256) {
            h_lds[tid] = 0.f;
#pragma unroll
            for (int j = 0; j < 4; ++j) xpb[j] = rowp[(long)j * HH + tid];
        }
        // gather offset for the half-stripe partial layout:
        // row n = g*8+r lives at (r>=4)*128 + g*4 + (r&3)
        const int ro = ((tid & 7) >> 2) * 128 + ((tid >> 3) << 2) + (tid & 3);
        LIGHT_BARRIER();

        for (int t0 = 0; t0 < TT; t0 += 4) {
#pragma unroll
            for (int j = 0; j < 4; ++j) {
                const int t = t0 + j;

                float4 h4[4];
#pragma unroll
                for (int c = 0; c < 4; ++c)
                    h4[c] = *(const float4*)&h_lds[ks * 16 + c * 4];

                float acc[8];
#pragma unroll
                for (int r = 0; r < 8; ++r) acc[r] = 0.f;
#pragma unroll
                for (int c = 0; c < 4; ++c)
#pragma unroll
                    for (int r = 0; r < 8; ++r)
                        acc[r] += w[r][c].x * h4[c].x + w[r][c].y * h4[c].y
                                + w[r][c].z * h4[c].z + w[r][c].w * h4[c].w;

                *(float4*)&part[ks * 256 + g * 4]       = make_float4(acc[0], acc[1], acc[2], acc[3]);
                *(float4*)&part[ks * 256 + 128 + g * 4] = make_float4(acc[4], acc[5], acc[6], acc[7]);
                LIGHT_BARRIER();

                if (tid < 256) {
                    float s0 = part[0 * 256 + ro] + part[1 * 256 + ro]
                             + part[2 * 256 + ro] + part[3 * 256 + ro];
                    float s1 = part[4 * 256 + ro] + part[5 * 256 + ro]
                             + part[6 * 256 + ro] + part[7 * 256 + ro];
                    float s2 = part[8 * 256 + ro] + part[9 * 256 + ro]
                             + part[10 * 256 + ro] + part[11 * 256 + ro];
                    float s3 = part[12 * 256 + ro] + part[13 * 256 + ro]
                             + part[14 * 256 + ro] + part[15 * 256 + ro];
                    float v = fast_tanh(((s0 + s1) + (s2 + s3)) + xpb[j]);
                    h_lds[tid] = v;
                    rowp[(long)t * HH + tid] = v;
                }
                if (j < 3) LIGHT_BARRIER();
            }

            // group tail: publish every 8 steps with a full drain; otherwise
            // a light barrier closes the 4th step.
            if (((t0 + 4) & 7) == 0) {
                asm volatile("s_waitcnt vmcnt(0) lgkmcnt(0)" ::: "memory");
                __builtin_amdgcn_s_barrier();
                if (tid == 0)
                    __hip_atomic_store(&flags[b], t0 + 4, __ATOMIC_RELEASE,
                                       __HIP_MEMORY_SCOPE_AGENT);
            } else {
                LIGHT_BARRIER();
            }

            // refill xp prefetch for the next group (4 steps of slack)
            if (tid < 256 && t0 + 4 < TT) {
#pragma unroll
                for (int j = 0; j < 4; ++j)
                    xpb[j] = rowp[(long)(t0 + 4 + j) * HH + tid];
            }
        }
    } else {
        // ------------------------- consumer -------------------------------
        __shared__ float h1_lds[256];
        __shared__ float o_lds[128];
        __shared__ float part2[16 * 132];
        __shared__ int   seen_sh;
        const int b = blockIdx.x - BB;

        float4 wi[4][4];
        float4 wh[4][2];
#pragma unroll
        for (int r = 0; r < 4; ++r) {
#pragma unroll
            for (int c = 0; c < 4; ++c)
                wi[r][c] = *(const float4*)&W_ih2[(g * 4 + r) * 256 + ks * 16 + c * 4];
#pragma unroll
            for (int c = 0; c < 2; ++c)
                wh[r][c] = *(const float4*)&W_hh2[(g * 4 + r) * 128 + ks * 8 + c * 4];
        }

        float bias = 0.f;
        if (tid < 128) {
            bias = b_ih2[tid] + b_hh2[tid];
            o_lds[tid] = 0.f;
        }
        const float* h1p = XH + (long)b * TT * HH;
        float* outp      = out + (long)b * TT * OO;
        LIGHT_BARRIER();

        int seen = 0;
        for (int t = 0; t < TT; ++t) {
            if (seen <= t) {
                // single-lane relaxed spin; ONE acquire load on success
                if (tid == 0) {
                    int s;
                    do {
                        s = __hip_atomic_load(&flags[b], __ATOMIC_RELAXED,
                                              __HIP_MEMORY_SCOPE_AGENT);
                    } while (s <= t);
                    s = __hip_atomic_load(&flags[b], __ATOMIC_ACQUIRE,
                                          __HIP_MEMORY_SCOPE_AGENT);
                    seen_sh = s;
                }
                LIGHT_BARRIER();
                seen = seen_sh;
            }
            // stage h1_t into LDS (1 KB, 64 lanes x float4)
            if (tid < 64)
                *(float4*)&h1_lds[tid * 4] = *(const float4*)&h1p[(long)t * HH + tid * 4];
            LIGHT_BARRIER();

            float4 h4[4];
#pragma unroll
            for (int c = 0; c < 4; ++c)
                h4[c] = *(const float4*)&h1_lds[ks * 16 + c * 4];
            float4 o4[2];
#pragma unroll
            for (int c = 0; c < 2; ++c)
                o4[c] = *(const float4*)&o_lds[ks * 8 + c * 4];

            float acc[4];
#pragma unroll
            for (int r = 0; r < 4; ++r) acc[r] = 0.f;
#pragma unroll
            for (int c = 0; c < 4; ++c)
#pragma unroll
                for (int r = 0; r < 4; ++r)
                    acc[r] += wi[r][c].x * h4[c].x + wi[r][c].y * h4[c].y
                            + wi[r][c].z * h4[c].z + wi[r][c].w * h4[c].w;
#pragma unroll
            for (int c = 0; c < 2; ++c)
#pragma unroll
                for (int r = 0; r < 4; ++r)
                    acc[r] += wh[r][c].x * o4[c].x + wh[r][c].y * o4[c].y
                            + wh[r][c].z * o4[c].z + wh[r][c].w * o4[c].w;

            *(float4*)&part2[ks * 132 + g * 4] = make_float4(acc[0], acc[1], acc[2], acc[3]);
            LIGHT_BARRIER();

            if (tid < 128) {
                float s = bias;
#pragma unroll
                for (int s16 = 0; s16 < 16; ++s16)
                    s += part2[s16 * 132 + tid];
                float v = fast_tanh(s);
                o_lds[tid] = v;
                outp[(long)t * OO + tid] = v;
            }
            // o_lds/part2 WAR vs next step is fenced by the stage barrier
        }
    }
}

// ---------------------------------------------------------------------------
extern "C" void kernel_launch(void* const* d_in, const int* in_sizes, int n_in,
                              void* d_out, int out_size, void* d_ws, size_t ws_size,
                              hipStream_t stream)
{
    const float* x     = (const float*)d_in[0];
    const float* W_ih1 = (const float*)d_in[1];
    const float* W_hh1 = (const float*)d_in[2];
    const float* b_ih1 = (const float*)d_in[3];
    const float* b_hh1 = (const float*)d_in[4];
    const float* W_ih2 = (const float*)d_in[5];
    const float* W_hh2 = (const float*)d_in[6];
    const float* b_ih2 = (const float*)d_in[7];
    const float* b_hh2 = (const float*)d_in[8];
    float* out = (float*)d_out;

    float* xp1 = (float*)d_ws;                         // [B*T, 256] = 128 MiB
    const size_t FLAG_OFF = (size_t)BB * TT * HH * sizeof(float);
    int* flags = (int*)((char*)d_ws + FLAG_OFF);       // [64] ints

    const int M = BB * TT;                             // 131072

    (void)hipMemsetAsync(flags, 0, BB * sizeof(int), stream);

    // Phase A: xp1 = x @ W_ih1^T + b_ih1 + b_hh1   -> ws
    dim3 gA(M / 128, HH / 128);
    gemm_bias<HH><<<gA, 256, 0, stream>>>(x, W_ih1, b_ih1, b_hh1, xp1);

    // Phase B: pipelined layer-1 recurrence (producers) + fused
    //          projection+layer-2 recurrence (consumers)
    rnn_pipe<<<2 * BB, 512, 0, stream>>>(W_hh1, W_ih2, W_hh2, b_ih2, b_hh2,
                                         xp1, out, flags);
}

// Round 4
// 1917.459 us; speedup vs baseline: 1.0867x; 1.0029x over previous
//
#include <hip/hip_runtime.h>
#include <math.h>

#define BB 64
#define TT 2048
#define II 256
#define HH 256
#define OO 128

// ---------------------------------------------------------------------------
// GEMM with bias: C[m,n] = sum_k A[m,k] * W[n,k] + b1[n] + b2[n]
// (unchanged; only used for xp1)
// ---------------------------------------------------------------------------
template<int N>
__global__ __launch_bounds__(256)
void gemm_bias(const float* __restrict__ A, const float* __restrict__ W,
               const float* __restrict__ b1, const float* __restrict__ b2,
               float* __restrict__ C)
{
    constexpr int K = 256;
    __shared__ float sA[16][132];
    __shared__ float sB[16][132];
    const int tid  = threadIdx.x;
    const long row0 = (long)blockIdx.x * 128;
    const int  col0 = blockIdx.y * 128;

    const int tm = tid & 15;
    const int tn = tid >> 4;

    float acc[8][8];
#pragma unroll
    for (int i = 0; i < 8; ++i)
#pragma unroll
        for (int j = 0; j < 8; ++j) acc[i][j] = 0.f;

    const int f0  = tid;
    const int f1  = tid + 256;
    const int am0 = f0 >> 2, ak0 = (f0 & 3) * 4;
    const int am1 = f1 >> 2, ak1 = (f1 & 3) * 4;

    for (int kt = 0; kt < K; kt += 16) {
        float4 a0 = *(const float4*)&A[(row0 + am0) * K + kt + ak0];
        float4 a1 = *(const float4*)&A[(row0 + am1) * K + kt + ak1];
        float4 w0 = *(const float4*)&W[(long)(col0 + am0) * K + kt + ak0];
        float4 w1 = *(const float4*)&W[(long)(col0 + am1) * K + kt + ak1];
        __syncthreads();
        sA[ak0+0][am0] = a0.x; sA[ak0+1][am0] = a0.y; sA[ak0+2][am0] = a0.z; sA[ak0+3][am0] = a0.w;
        sA[ak1+0][am1] = a1.x; sA[ak1+1][am1] = a1.y; sA[ak1+2][am1] = a1.z; sA[ak1+3][am1] = a1.w;
        sB[ak0+0][am0] = w0.x; sB[ak0+1][am0] = w0.y; sB[ak0+2][am0] = w0.z; sB[ak0+3][am0] = w0.w;
        sB[ak1+0][am1] = w1.x; sB[ak1+1][am1] = w1.y; sB[ak1+2][am1] = w1.z; sB[ak1+3][am1] = w1.w;
        __syncthreads();
#pragma unroll
        for (int k = 0; k < 16; ++k) {
            float4 av0 = *(const float4*)&sA[k][tm * 8];
            float4 av1 = *(const float4*)&sA[k][tm * 8 + 4];
            float4 bv0 = *(const float4*)&sB[k][tn * 8];
            float4 bv1 = *(const float4*)&sB[k][tn * 8 + 4];
            float am[8] = {av0.x, av0.y, av0.z, av0.w, av1.x, av1.y, av1.z, av1.w};
            float bn[8] = {bv0.x, bv0.y, bv0.z, bv0.w, bv1.x, bv1.y, bv1.z, bv1.w};
#pragma unroll
            for (int i = 0; i < 8; ++i)
#pragma unroll
                for (int j = 0; j < 8; ++j)
                    acc[i][j] += am[i] * bn[j];
        }
    }

    float bias[8];
#pragma unroll
    for (int j = 0; j < 8; ++j) {
        int col = col0 + tn * 8 + j;
        bias[j] = b1[col] + b2[col];
    }
#pragma unroll
    for (int i = 0; i < 8; ++i) {
        long row = row0 + tm * 8 + i;
        float4 v0, v1;
        v0.x = acc[i][0] + bias[0]; v0.y = acc[i][1] + bias[1];
        v0.z = acc[i][2] + bias[2]; v0.w = acc[i][3] + bias[3];
        v1.x = acc[i][4] + bias[4]; v1.y = acc[i][5] + bias[5];
        v1.z = acc[i][6] + bias[6]; v1.w = acc[i][7] + bias[7];
        *(float4*)&C[row * N + col0 + tn * 8]     = v0;
        *(float4*)&C[row * N + col0 + tn * 8 + 4] = v1;
    }
}

__device__ __forceinline__ float fast_tanh(float x) {
    float e = __expf(2.f * x);
    return 1.f - 2.f / (e + 1.f);
}

// Light barrier: LDS-ordering only. Unlike __syncthreads(), does NOT drain
// vmcnt — global loads/stores stay in flight across it.
#define LIGHT_BARRIER() do {                                       \
    asm volatile("s_waitcnt lgkmcnt(0)" ::: "memory");             \
    __builtin_amdgcn_s_barrier();                                  \
} while (0)

// Pin a float4's components into VGPRs: severs rematerialization provenance
// so the compiler cannot re-load the value from global memory each step.
// (Round-3 diagnosis: VGPR_Count=84 < the 128 floats of the producer's W
// slice -> compiler was re-reading 256 KB/step/CU from L2 = ~1500 cyc/step,
// the dominant stall. Only the register file has that bandwidth.)
#define PIN4(v) asm volatile("" : "+v"((v).x), "+v"((v).y), "+v"((v).z), "+v"((v).w))

// ---------------------------------------------------------------------------
// Pipelined RNN: 128 WGs x 512 threads.
//   WG b in [0,64):    producer — layer-1 recurrence for batch b.
//   WG b+64:           consumer — layer-2 projection+recurrence for batch b.
// Round-3 change: register-pin the per-thread weight slices (w / wi / wh)
// after the one-time load; __launch_bounds__(512,2) grants the 256-VGPR
// budget at our structural occupancy of 2 waves/SIMD (pressure ~190).
// ---------------------------------------------------------------------------
__global__ __launch_bounds__(512, 2)
void rnn_pipe(const float* __restrict__ W_hh1,
              const float* __restrict__ W_ih2,
              const float* __restrict__ W_hh2,
              const float* __restrict__ b_ih2,
              const float* __restrict__ b_hh2,
              float* __restrict__ XH,          // xp1 in / h1 out (in place)
              float* __restrict__ out,         // [B*T, OO]
              int* __restrict__ flags)         // [BB], pre-zeroed
{
    const int tid = threadIdx.x;
    const int g   = tid & 31;
    const int ks  = tid >> 5;

    if (blockIdx.x < BB) {
        // ------------------------- producer -------------------------------
        __shared__ float h_lds[256];
        __shared__ float part[16 * 256];
        const int b = blockIdx.x;

        float4 w[8][4];
#pragma unroll
        for (int r = 0; r < 8; ++r)
#pragma unroll
            for (int c = 0; c < 4; ++c)
                w[r][c] = *(const float4*)&W_hh1[(g * 8 + r) * 256 + ks * 16 + c * 4];
        // force the whole 128-float slice to be register-resident
#pragma unroll
        for (int r = 0; r < 8; ++r)
#pragma unroll
            for (int c = 0; c < 4; ++c)
                PIN4(w[r][c]);

        float* rowp = XH + (long)b * TT * HH;
        float xpb[4] = {0.f, 0.f, 0.f, 0.f};
        if (tid < 256) {
            h_lds[tid] = 0.f;
#pragma unroll
            for (int j = 0; j < 4; ++j) xpb[j] = rowp[(long)j * HH + tid];
        }
        // gather offset for the half-stripe partial layout:
        // row n = g*8+r lives at (r>=4)*128 + g*4 + (r&3)
        const int ro = ((tid & 7) >> 2) * 128 + ((tid >> 3) << 2) + (tid & 3);
        LIGHT_BARRIER();

        for (int t0 = 0; t0 < TT; t0 += 4) {
#pragma unroll
            for (int j = 0; j < 4; ++j) {
                const int t = t0 + j;

                float4 h4[4];
#pragma unroll
                for (int c = 0; c < 4; ++c)
                    h4[c] = *(const float4*)&h_lds[ks * 16 + c * 4];

                float acc[8];
#pragma unroll
                for (int r = 0; r < 8; ++r) acc[r] = 0.f;
#pragma unroll
                for (int c = 0; c < 4; ++c)
#pragma unroll
                    for (int r = 0; r < 8; ++r)
                        acc[r] += w[r][c].x * h4[c].x + w[r][c].y * h4[c].y
                                + w[r][c].z * h4[c].z + w[r][c].w * h4[c].w;

                *(float4*)&part[ks * 256 + g * 4]       = make_float4(acc[0], acc[1], acc[2], acc[3]);
                *(float4*)&part[ks * 256 + 128 + g * 4] = make_float4(acc[4], acc[5], acc[6], acc[7]);
                LIGHT_BARRIER();

                if (tid < 256) {
                    float s0 = part[0 * 256 + ro] + part[1 * 256 + ro]
                             + part[2 * 256 + ro] + part[3 * 256 + ro];
                    float s1 = part[4 * 256 + ro] + part[5 * 256 + ro]
                             + part[6 * 256 + ro] + part[7 * 256 + ro];
                    float s2 = part[8 * 256 + ro] + part[9 * 256 + ro]
                             + part[10 * 256 + ro] + part[11 * 256 + ro];
                    float s3 = part[12 * 256 + ro] + part[13 * 256 + ro]
                             + part[14 * 256 + ro] + part[15 * 256 + ro];
                    float v = fast_tanh(((s0 + s1) + (s2 + s3)) + xpb[j]);
                    h_lds[tid] = v;
                    rowp[(long)t * HH + tid] = v;
                }
                if (j < 3) LIGHT_BARRIER();
            }

            // group tail: publish every 8 steps with a full drain; otherwise
            // a light barrier closes the 4th step.
            if (((t0 + 4) & 7) == 0) {
                asm volatile("s_waitcnt vmcnt(0) lgkmcnt(0)" ::: "memory");
                __builtin_amdgcn_s_barrier();
                if (tid == 0)
                    __hip_atomic_store(&flags[b], t0 + 4, __ATOMIC_RELEASE,
                                       __HIP_MEMORY_SCOPE_AGENT);
            } else {
                LIGHT_BARRIER();
            }

            // refill xp prefetch for the next group (4 steps of slack)
            if (tid < 256 && t0 + 4 < TT) {
#pragma unroll
                for (int j = 0; j < 4; ++j)
                    xpb[j] = rowp[(long)(t0 + 4 + j) * HH + tid];
            }
        }
    } else {
        // ------------------------- consumer -------------------------------
        __shared__ float h1_lds[256];
        __shared__ float o_lds[128];
        __shared__ float part2[16 * 132];
        __shared__ int   seen_sh;
        const int b = blockIdx.x - BB;

        float4 wi[4][4];
        float4 wh[4][2];
#pragma unroll
        for (int r = 0; r < 4; ++r) {
#pragma unroll
            for (int c = 0; c < 4; ++c)
                wi[r][c] = *(const float4*)&W_ih2[(g * 4 + r) * 256 + ks * 16 + c * 4];
#pragma unroll
            for (int c = 0; c < 2; ++c)
                wh[r][c] = *(const float4*)&W_hh2[(g * 4 + r) * 128 + ks * 8 + c * 4];
        }
        // pin the 96-float slice register-resident
#pragma unroll
        for (int r = 0; r < 4; ++r) {
#pragma unroll
            for (int c = 0; c < 4; ++c) PIN4(wi[r][c]);
#pragma unroll
            for (int c = 0; c < 2; ++c) PIN4(wh[r][c]);
        }

        float bias = 0.f;
        if (tid < 128) {
            bias = b_ih2[tid] + b_hh2[tid];
            o_lds[tid] = 0.f;
        }
        const float* h1p = XH + (long)b * TT * HH;
        float* outp      = out + (long)b * TT * OO;
        LIGHT_BARRIER();

        int seen = 0;
        for (int t = 0; t < TT; ++t) {
            if (seen <= t) {
                // single-lane relaxed spin; ONE acquire load on success
                if (tid == 0) {
                    int s;
                    do {
                        s = __hip_atomic_load(&flags[b], __ATOMIC_RELAXED,
                                              __HIP_MEMORY_SCOPE_AGENT);
                    } while (s <= t);
                    s = __hip_atomic_load(&flags[b], __ATOMIC_ACQUIRE,
                                          __HIP_MEMORY_SCOPE_AGENT);
                    seen_sh = s;
                }
                LIGHT_BARRIER();
                seen = seen_sh;
            }
            // stage h1_t into LDS (1 KB, 64 lanes x float4)
            if (tid < 64)
                *(float4*)&h1_lds[tid * 4] = *(const float4*)&h1p[(long)t * HH + tid * 4];
            LIGHT_BARRIER();

            float4 h4[4];
#pragma unroll
            for (int c = 0; c < 4; ++c)
                h4[c] = *(const float4*)&h1_lds[ks * 16 + c * 4];
            float4 o4[2];
#pragma unroll
            for (int c = 0; c < 2; ++c)
                o4[c] = *(const float4*)&o_lds[ks * 8 + c * 4];

            float acc[4];
#pragma unroll
            for (int r = 0; r < 4; ++r) acc[r] = 0.f;
#pragma unroll
            for (int c = 0; c < 4; ++c)
#pragma unroll
                for (int r = 0; r < 4; ++r)
                    acc[r] += wi[r][c].x * h4[c].x + wi[r][c].y * h4[c].y
                            + wi[r][c].z * h4[c].z + wi[r][c].w * h4[c].w;
#pragma unroll
            for (int c = 0; c < 2; ++c)
#pragma unroll
                for (int r = 0; r < 4; ++r)
                    acc[r] += wh[r][c].x * o4[c].x + wh[r][c].y * o4[c].y
                            + wh[r][c].z * o4[c].z + wh[r][c].w * o4[c].w;

            *(float4*)&part2[ks * 132 + g * 4] = make_float4(acc[0], acc[1], acc[2], acc[3]);
            LIGHT_BARRIER();

            if (tid < 128) {
                float s = bias;
#pragma unroll
                for (int s16 = 0; s16 < 16; ++s16)
                    s += part2[s16 * 132 + tid];
                float v = fast_tanh(s);
                o_lds[tid] = v;
                outp[(long)t * OO + tid] = v;
            }
            // o_lds/part2 WAR vs next step is fenced by the stage barrier
        }
    }
}

// ---------------------------------------------------------------------------
extern "C" void kernel_launch(void* const* d_in, const int* in_sizes, int n_in,
                              void* d_out, int out_size, void* d_ws, size_t ws_size,
                              hipStream_t stream)
{
    const float* x     = (const float*)d_in[0];
    const float* W_ih1 = (const float*)d_in[1];
    const float* W_hh1 = (const float*)d_in[2];
    const float* b_ih1 = (const float*)d_in[3];
    const float* b_hh1 = (const float*)d_in[4];
    const float* W_ih2 = (const float*)d_in[5];
    const float* W_hh2 = (const float*)d_in[6];
    const float* b_ih2 = (const float*)d_in[7];
    const float* b_hh2 = (const float*)d_in[8];
    float* out = (float*)d_out;

    float* xp1 = (float*)d_ws;                         // [B*T, 256] = 128 MiB
    const size_t FLAG_OFF = (size_t)BB * TT * HH * sizeof(float);
    int* flags = (int*)((char*)d_ws + FLAG_OFF);       // [64] ints

    const int M = BB * TT;                             // 131072

    (void)hipMemsetAsync(flags, 0, BB * sizeof(int), stream);

    // Phase A: xp1 = x @ W_ih1^T + b_ih1 + b_hh1   -> ws
    dim3 gA(M / 128, HH / 128);
    gemm_bias<HH><<<gA, 256, 0, stream>>>(x, W_ih1, b_ih1, b_hh1, xp1);

    // Phase B: pipelined layer-1 recurrence (producers) + fused
    //          projection+layer-2 recurrence (consumers)
    rnn_pipe<<<2 * BB, 512, 0, stream>>>(W_hh1, W_ih2, W_hh2, b_ih2, b_hh2,
                                         xp1, out, flags);
}